// Round 15
// baseline (68.862 us; speedup 1.0000x reference)
//
#include <hip/hip_runtime.h>
#include <hip/hip_fp16.h>

#define DDIM 128
#define ACC_BLOCKS 2048
#define NWAVES (ACC_BLOCKS * 4)
#define NHALF (NWAVES * 2)         // 16384 half-walkers (2 per wave)
#define RED_BLOCKS 64

typedef unsigned int uint;
typedef unsigned short ushort;
typedef __attribute__((ext_vector_type(8))) short bf16x8;
typedef __attribute__((ext_vector_type(4))) float f32x4;

static __device__ __forceinline__ ushort f2bf(float x) {
    uint u = __float_as_uint(x);
    u += 0x7fffu + ((u >> 16) & 1u);   // RTN-even
    return (ushort)(u >> 16);
}

// ---------------- Kernel 0: fused prep (rowptr + item stream + zrow + done) ----------------
// Node i's stream slot = rowptr[i]+i (Wh row, flush iff degree 0); edge x's slot
// = x + segs[x] + 1 (Mh row, flush iff last edge of its node). Rows: 256 B fp16.
__global__ __launch_bounds__(256) void prep(
    const int* __restrict__ segs,
    const int* __restrict__ node_ids,
    const int* __restrict__ neighbor_ids,
    int* __restrict__ rowptr,
    int* __restrict__ items,
    int* __restrict__ done,
    uint* __restrict__ zrow,
    int N, int E, int whoff, int mhoff, int zpad)
{
    const int x = blockIdx.x * blockDim.x + threadIdx.x;
    if (x == 0) *done = 0;
    if (x < 64) zrow[x] = 0u;             // 256 B zero row (pad gather target)
    if (x >= E) return;

    const int sc = segs[x];
    const int sp = (x == 0) ? -1 : segs[x - 1];
    const int sn = (x + 1 < E) ? segs[x + 1] : N;   // sentinel > any node id

    items[x + sc + 1] = (mhoff + neighbor_ids[x] * 256) | ((sn != sc) ? (int)0x80000000 : 0);

    for (int i = sp + 1; i <= sc; ++i) {
        rowptr[i] = x;
        items[x + i] = (whoff + node_ids[i] * 256) | ((i < sc) ? (int)0x80000000 : 0);
    }
    if (x == E - 1) {
        for (int i = sc + 1; i <= N; ++i) {
            rowptr[i] = E;
            if (i < N) items[E + i] = (whoff + node_ids[i] * 256) | (int)0x80000000;
        }
#pragma unroll
        for (int q = 0; q < 32; ++q) items[N + E + q] = zpad;   // pad: zero row, no flush
    }
}

// ---------------- Kernel 1: MFMA precompute Wh/Mh (fp16 tables) + wstart ----------------
static __device__ __forceinline__ bf16x8 load_frag8(const float* base) {
    const float4 p = *reinterpret_cast<const float4*>(base);
    const float4 q = *reinterpret_cast<const float4*>(base + 4);
    bf16x8 f;
    f[0] = (short)f2bf(p.x); f[1] = (short)f2bf(p.y);
    f[2] = (short)f2bf(p.z); f[3] = (short)f2bf(p.w);
    f[4] = (short)f2bf(q.x); f[5] = (short)f2bf(q.y);
    f[6] = (short)f2bf(q.z); f[7] = (short)f2bf(q.w);
    return f;
}

__global__ __launch_bounds__(256) void precompute_mfma(
    const float* __restrict__ impact,
    const float* __restrict__ W,
    const float* __restrict__ Mm,
    __half* __restrict__ WhH,
    __half* __restrict__ MhH,
    const int* __restrict__ rowptr,
    int* __restrict__ wstart,
    int T, int N, int K)
{
    // spare-thread work: half-walker start table (node-aligned, equal item spacing)
    const int gid = blockIdx.x * 256 + threadIdx.x;
    if (gid <= NHALF) {
        const int t = (int)(((long long)gid * K) / NHALF);
        int lo = 0, hi = N;
        while (lo < hi) {
            const int mid = (lo + hi) >> 1;
            if (rowptr[mid] + mid < t) lo = mid + 1; else hi = mid;
        }
        wstart[gid] = rowptr[lo] + lo;     // lo==N -> K
    }

    const int lane = threadIdx.x & 63;
    const int wv   = threadIdx.x >> 6;       // 0..3 -> d tiles {2wv, 2wv+1}
    const int t0   = blockIdx.x * 32;
    const int r16  = lane & 15;
    const int kg   = lane >> 4;              // 0..3

    bf16x8 A[2][4];
#pragma unroll
    for (int rt = 0; rt < 2; ++rt) {
        int t = t0 + rt * 16 + r16;
        if (t >= T) t = T - 1;               // clamp; writes masked below
        const float* abase = impact + (size_t)t * DDIM + kg * 8;
#pragma unroll
        for (int k0i = 0; k0i < 4; ++k0i)
            A[rt][k0i] = load_frag8(abase + k0i * 32);
    }

#pragma unroll
    for (int dti = 0; dti < 2; ++dti) {
        const int d0 = (wv * 2 + dti) * 16;
#pragma unroll
        for (int m = 0; m < 2; ++m) {
            const float* mat = (m == 0) ? W : Mm;
            __half* out = (m == 0) ? WhH : MhH;
            const float* bbase = mat + (size_t)(d0 + r16) * DDIM + kg * 8;
            f32x4 acc0 = {0.f, 0.f, 0.f, 0.f};
            f32x4 acc1 = {0.f, 0.f, 0.f, 0.f};
#pragma unroll
            for (int k0i = 0; k0i < 4; ++k0i) {
                const bf16x8 b = load_frag8(bbase + k0i * 32);
                acc0 = __builtin_amdgcn_mfma_f32_16x16x32_bf16(A[0][k0i], b, acc0, 0, 0, 0);
                acc1 = __builtin_amdgcn_mfma_f32_16x16x32_bf16(A[1][k0i], b, acc1, 0, 0, 0);
            }
            const int dcol = d0 + r16;
#pragma unroll
            for (int r = 0; r < 4; ++r) {
                const int tr0 = t0 + kg * 4 + r;
                const int tr1 = tr0 + 16;
                if (tr0 < T) out[(size_t)tr0 * DDIM + dcol] = __float2half(acc0[r]);
                if (tr1 < T) out[(size_t)tr1 * DDIM + dcol] = __float2half(acc1[r]);
            }
        }
    }
}

// ---------------- Kernel 2: half-wave pair-gather accumulate ----------------
// Lanes 0-31 walk stream A, lanes 32-63 stream B (both node-snapped). Lane =
// uint2 = 4 fp16 features of its half's row -> ONE dwordx2 gather covers TWO
// 256 B rows (halves TA address work/item). Items scalar; flush exec-masked
// per half under a scalar branch; ragged ends padded with a zero row.
__global__ __launch_bounds__(256, 8) void accumulate_pairs(
    const char* __restrict__ tab,
    const int* __restrict__ items,
    const int* __restrict__ wstart,
    float* __restrict__ partials,
    int zpad)
{
    const int tid  = threadIdx.x;
    const int lane = tid & 63;
    const int wv   = __builtin_amdgcn_readfirstlane(tid >> 6);
    const int w    = blockIdx.x * 4 + wv;

    int kA        = __builtin_amdgcn_readfirstlane(wstart[2 * w]);
    const int kAe = __builtin_amdgcn_readfirstlane(wstart[2 * w + 1]);
    int kB        = kAe;
    const int kBe = __builtin_amdgcn_readfirstlane(wstart[2 * w + 2]);

    const bool inB = lane >= 32;
    const uint vb  = (uint)(lane & 31) * 8u;   // 8 B per lane within the row

    const __half2 z2 = __floats2half2_rn(0.f, 0.f);
    __half2 c0 = z2, c1 = z2;
    float a0 = 0.f, a1 = 0.f, a2 = 0.f, a3 = 0.f;

#define LOADI8(WA, WB) { \
    _Pragma("unroll") \
    for (int j = 0; j < 8; ++j) { \
        const int ta_ = items[kA + j]; \
        const int tb_ = items[kB + j]; \
        WA[j] = (kA + j < kAe) ? ta_ : zpad; \
        WB[j] = (kB + j < kBe) ? tb_ : zpad; \
    } \
    kA = min(kA + 8, kAe); \
    kB = min(kB + 8, kBe); }

#define GATHER8(V, WA, WB) { \
    _Pragma("unroll") \
    for (int j = 0; j < 8; ++j) { \
        const int sa_ = WA[j] & 0x7fffffff; \
        const int sb_ = WB[j] & 0x7fffffff; \
        const uint off_ = (uint)(inB ? sb_ : sa_) + vb; \
        V[j] = *reinterpret_cast<const uint2*>(tab + off_); \
    } }

#define ACC8(V, WA, WB) { \
    _Pragma("unroll") \
    for (int j = 0; j < 8; ++j) { \
        c0 = __hadd2(c0, *reinterpret_cast<const __half2*>(&V[j].x)); \
        c1 = __hadd2(c1, *reinterpret_cast<const __half2*>(&V[j].y)); \
        const bool fA_ = WA[j] < 0; \
        const bool fB_ = WB[j] < 0; \
        if (fA_ || fB_) { \
            const bool myf_ = inB ? fB_ : fA_; \
            if (myf_) { \
                const float2 f0_ = __half22float2(c0); \
                const float2 f1_ = __half22float2(c1); \
                a0 += fmaxf(f0_.x, 0.f); a1 += fmaxf(f0_.y, 0.f); \
                a2 += fmaxf(f1_.x, 0.f); a3 += fmaxf(f1_.y, 0.f); \
                c0 = z2; c1 = z2; \
            } \
        } \
    } }

    if (kA < kAe || kB < kBe) {
        int wa0[8], wb0[8], wa1[8], wb1[8];
        uint2 v0[8], v1[8];
        LOADI8(wa0, wb0);
        GATHER8(v0, wa0, wb0);
        for (;;) {
            const bool more1 = (kA < kAe) || (kB < kBe);
            if (more1) { LOADI8(wa1, wb1); GATHER8(v1, wa1, wb1); }
            ACC8(v0, wa0, wb0);
            if (!more1) break;
            const bool more2 = (kA < kAe) || (kB < kBe);
            if (more2) { LOADI8(wa0, wb0); GATHER8(v0, wa0, wb0); }
            ACC8(v1, wa1, wb1);
            if (!more2) break;
        }
    }

    {   // halves end node-aligned -> c==0 (zpad rows add 0); relu(0)=0 safe
        const float2 f0 = __half22float2(c0);
        const float2 f1 = __half22float2(c1);
        a0 += fmaxf(f0.x, 0.f); a1 += fmaxf(f0.y, 0.f);
        a2 += fmaxf(f1.x, 0.f); a3 += fmaxf(f1.y, 0.f);
    }

    __shared__ float red[8][DDIM];
    *reinterpret_cast<float4*>(&red[wv * 2 + (inB ? 1 : 0)][(lane & 31) * 4]) =
        make_float4(a0, a1, a2, a3);
    __syncthreads();
    if (tid < DDIM) {
        float s = 0.f;
#pragma unroll
        for (int g = 0; g < 8; ++g) s += red[g][tid];
        partials[(size_t)blockIdx.x * DDIM + tid] = s;
    }
}

// ---------------- Kernel 3: reduce partials + last-block softmax ----------------
__global__ __launch_bounds__(256) void reduce_softmax(
    const float* __restrict__ partials, float* __restrict__ out2,
    float* __restrict__ out, int* __restrict__ done, int nb)
{
    const int tid = threadIdx.x;
    const int d = tid & (DDIM - 1);
    const int h = tid >> 7;                  // 0..1
    {
        const int rows = nb / RED_BLOCKS;    // 32
        const int r0 = blockIdx.x * rows;
        float s = 0.f;
        for (int r = r0 + h; r < r0 + rows; r += 2)
            s += partials[(size_t)r * DDIM + d];
        __shared__ float red[2][DDIM];
        red[h][d] = s;
        __syncthreads();
        if (tid < DDIM)
            out2[(size_t)blockIdx.x * DDIM + tid] = red[0][tid] + red[1][tid];
    }
    __threadfence();
    __shared__ int isLast;
    if (tid == 0) {
        const int v = atomicAdd(done, 1);
        isLast = (v == RED_BLOCKS - 1) ? 1 : 0;
    }
    __syncthreads();
    if (!isLast) return;
    __threadfence();                          // acquire

    float s = 0.f;
    for (int b = h; b < RED_BLOCKS; b += 2)
        s += out2[(size_t)b * DDIM + d];
    __shared__ float r2[2][DDIM];
    r2[h][d] = s;
    __syncthreads();

    __shared__ float vec[DDIM];
    __shared__ float tmp[DDIM];
    if (tid < DDIM) { const float v = r2[0][tid] + r2[1][tid]; vec[tid] = v; tmp[tid] = v; }
    __syncthreads();
    for (int o = 64; o > 0; o >>= 1) {
        if (tid < o) tmp[tid] = fmaxf(tmp[tid], tmp[tid + o]);
        __syncthreads();
    }
    const float mx = tmp[0];
    __syncthreads();
    float ev = 0.f;
    if (tid < DDIM) { ev = expf(vec[tid] - mx); tmp[tid] = ev; }
    __syncthreads();
    for (int o = 64; o > 0; o >>= 1) {
        if (tid < o) tmp[tid] += tmp[tid + o];
        __syncthreads();
    }
    if (tid < DDIM) out[tid] = ev / tmp[0];
}

extern "C" void kernel_launch(void* const* d_in, const int* in_sizes, int n_in,
                              void* d_out, int out_size, void* d_ws, size_t ws_size,
                              hipStream_t stream) {
    const float* impact        = (const float*)d_in[0];
    const float* W             = (const float*)d_in[1];
    const float* Mm            = (const float*)d_in[2];
    const int*   node_ids      = (const int*)d_in[3];
    const int*   neighbor_ids  = (const int*)d_in[4];
    const int*   neighbor_segs = (const int*)d_in[5];

    const int T = in_sizes[0] / DDIM;   // 10000
    const int N = in_sizes[3];          // 50000
    const int E = in_sizes[4];          // 800000
    const int K = N + E;

    char* ws = (char*)d_ws;
    size_t off = 0;
    const int whoff = (int)off;
    __half* WhH = (__half*)(ws + off);  off += (size_t)T * DDIM * sizeof(__half);   // 2.56 MB
    const int mhoff = (int)off;
    __half* MhH = (__half*)(ws + off);  off += (size_t)T * DDIM * sizeof(__half);   // 2.56 MB
    const int zoff = (int)off;
    uint* zrow = (uint*)(ws + off);     off += 64 * sizeof(uint);                   // 256 B
    float* partials = (float*)(ws + off); off += (size_t)ACC_BLOCKS * DDIM * sizeof(float);
    float* part2    = (float*)(ws + off); off += (size_t)RED_BLOCKS * DDIM * sizeof(float);
    int*   rowptr   = (int*)(ws + off);   off += (size_t)(N + 1) * sizeof(int);
    int*   done     = (int*)(ws + off);   off += 256;
    off = (off + 255) & ~(size_t)255;
    int*   items    = (int*)(ws + off);   off += (size_t)(K + 32) * sizeof(int);
    int*   wstart   = (int*)(ws + off);   off += (size_t)(NHALF + 1) * sizeof(int);
    float* outf     = (float*)d_out;

    prep<<<(E + 255) / 256, 256, 0, stream>>>(
        neighbor_segs, node_ids, neighbor_ids, rowptr, items, done, zrow,
        N, E, whoff, mhoff, zoff);
    precompute_mfma<<<(T + 31) / 32, 256, 0, stream>>>(
        impact, W, Mm, WhH, MhH, rowptr, wstart, T, N, K);
    accumulate_pairs<<<ACC_BLOCKS, 256, 0, stream>>>(ws, items, wstart, partials, zoff);
    reduce_softmax<<<RED_BLOCKS, 256, 0, stream>>>(partials, part2, outf, done, ACC_BLOCKS);
}

// Round 16
// 57.297 us; speedup vs baseline: 1.2019x; 1.2019x over previous
//
#include <hip/hip_runtime.h>
#include <hip/hip_fp16.h>

#define DDIM 128
#define ACC_BLOCKS 2048
#define NWALK (ACC_BLOCKS * 4)     // full-wave walkers
#define RED_BLOCKS 64

typedef unsigned int uint;
typedef unsigned short ushort;
typedef __attribute__((ext_vector_type(8))) short bf16x8;
typedef __attribute__((ext_vector_type(4))) float f32x4;

static __device__ __forceinline__ ushort f2bf(float x) {
    uint u = __float_as_uint(x);
    u += 0x7fffu + ((u >> 16) & 1u);   // RTN-even
    return (ushort)(u >> 16);
}

static __device__ __forceinline__ bf16x8 load_frag8(const float* base) {
    const float4 p = *reinterpret_cast<const float4*>(base);
    const float4 q = *reinterpret_cast<const float4*>(base + 4);
    bf16x8 f;
    f[0] = (short)f2bf(p.x); f[1] = (short)f2bf(p.y);
    f[2] = (short)f2bf(p.z); f[3] = (short)f2bf(p.w);
    f[4] = (short)f2bf(q.x); f[5] = (short)f2bf(q.y);
    f[6] = (short)f2bf(q.z); f[7] = (short)f2bf(q.w);
    return f;
}

// ---------------- Kernel A (fat): precompute_mfma (blocks < PB) + prep (rest) ----------
// prep: node i's stream slot = (first edge of i) + i (Wh row, flush iff degree 0);
// edge x's slot = x + segs[x] + 1 (Mh row, flush iff last edge of its node).
// wstart[w]: snap target edge t=w*E/NWALK to its node n=segs[t]; start =
// lower_bound(segs, n) + n. Derived from segs only — no rowptr array at all.
__global__ __launch_bounds__(256) void fat_prep_precompute(
    const float* __restrict__ impact,
    const float* __restrict__ W,
    const float* __restrict__ Mm,
    __half* __restrict__ WhH,
    __half* __restrict__ MhH,
    const int* __restrict__ segs,
    const int* __restrict__ node_ids,
    const int* __restrict__ neighbor_ids,
    int* __restrict__ items,
    int* __restrict__ wstart,
    int* __restrict__ done,
    int T, int N, int E, int PB, int whoff, int mhoff)
{
    if ((int)blockIdx.x >= PB) {
        // ---------------- prep part ----------------
        const int x = ((int)blockIdx.x - PB) * 256 + (int)threadIdx.x;
        const int K = N + E;
        if (x == 0) *done = 0;

        if (x < E) {
            const int sc = segs[x];
            const int sp = (x == 0) ? -1 : segs[x - 1];
            const int sn = (x + 1 < E) ? segs[x + 1] : N;   // sentinel > any node

            items[x + sc + 1] = (mhoff + neighbor_ids[x] * 256)
                              | ((sn != sc) ? (int)0x80000000 : 0);

            for (int i = sp + 1; i <= sc; ++i)              // boundary nodes
                items[x + i] = (whoff + node_ids[i] * 256)
                             | ((i < sc) ? (int)0x80000000 : 0);

            if (x == E - 1) {
                for (int i = sc + 1; i < N; ++i)            // trailing deg-0 nodes
                    items[E + i] = (whoff + node_ids[i] * 256) | (int)0x80000000;
#pragma unroll
                for (int q = 0; q < 32; ++q) items[K + q] = whoff;  // pad
            }
        } else if (x <= E + NWALK) {
            const int w = x - E;
            int ws;
            if (w == 0) ws = 0;
            else {
                const long long t = (long long)w * E / NWALK;
                if (t >= E) ws = K;
                else {
                    const int n = segs[(int)t];
                    int lo = 0, hi = (int)t;
                    while (lo < hi) {
                        const int mid = (lo + hi) >> 1;
                        if (segs[mid] < n) lo = mid + 1; else hi = mid;
                    }
                    ws = lo + n;           // node n's Wh-item position
                }
            }
            wstart[w] = ws;
        }
        return;
    }

    // ---------------- precompute_mfma part ----------------
    const int lane = threadIdx.x & 63;
    const int wv   = threadIdx.x >> 6;       // 0..3 -> d tiles {2wv, 2wv+1}
    const int t0   = (int)blockIdx.x * 32;
    const int r16  = lane & 15;
    const int kg   = lane >> 4;              // 0..3

    bf16x8 A[2][4];
#pragma unroll
    for (int rt = 0; rt < 2; ++rt) {
        int t = t0 + rt * 16 + r16;
        if (t >= T) t = T - 1;               // clamp; writes masked below
        const float* abase = impact + (size_t)t * DDIM + kg * 8;
#pragma unroll
        for (int k0i = 0; k0i < 4; ++k0i)
            A[rt][k0i] = load_frag8(abase + k0i * 32);
    }

#pragma unroll
    for (int dti = 0; dti < 2; ++dti) {
        const int d0 = (wv * 2 + dti) * 16;
#pragma unroll
        for (int m = 0; m < 2; ++m) {
            const float* mat = (m == 0) ? W : Mm;
            __half* out = (m == 0) ? WhH : MhH;
            const float* bbase = mat + (size_t)(d0 + r16) * DDIM + kg * 8;
            f32x4 acc0 = {0.f, 0.f, 0.f, 0.f};
            f32x4 acc1 = {0.f, 0.f, 0.f, 0.f};
#pragma unroll
            for (int k0i = 0; k0i < 4; ++k0i) {
                const bf16x8 b = load_frag8(bbase + k0i * 32);
                acc0 = __builtin_amdgcn_mfma_f32_16x16x32_bf16(A[0][k0i], b, acc0, 0, 0, 0);
                acc1 = __builtin_amdgcn_mfma_f32_16x16x32_bf16(A[1][k0i], b, acc1, 0, 0, 0);
            }
            const int dcol = d0 + r16;
#pragma unroll
            for (int r = 0; r < 4; ++r) {
                const int tr0 = t0 + kg * 4 + r;
                const int tr1 = tr0 + 16;
                if (tr0 < T) out[(size_t)tr0 * DDIM + dcol] = __float2half(acc0[r]);
                if (tr1 < T) out[(size_t)tr1 * DDIM + dcol] = __float2half(acc1[r]);
            }
        }
    }
}

// ---------------- Kernel B: pipelined item-stream gather-accumulate (R13 verbatim) ----
__global__ __launch_bounds__(256, 8) void accumulate_items(
    const char* __restrict__ tab,
    const int* __restrict__ items,
    const int* __restrict__ wstart,
    float* __restrict__ partials)
{
    const int lane = threadIdx.x & 63;
    const int wv   = __builtin_amdgcn_readfirstlane(threadIdx.x >> 6);
    const int w    = blockIdx.x * 4 + wv;

    const uint lb = (uint)lane << 2;     // 4 B per lane (2 fp16)

    const __half2 zero2 = __floats2half2_rn(0.f, 0.f);
    __half2 cc = zero2;
    float a0 = 0.f, a1 = 0.f;

    int k = __builtin_amdgcn_readfirstlane(wstart[w]);
    const int kend = __builtin_amdgcn_readfirstlane(wstart[w + 1]);

#define GATH(IW) (*reinterpret_cast<const __half2*>(tab + (((uint)(IW)) & 0x7fffffffu) + lb))
#define ACC(IW, V) { \
    cc = __hadd2(cc, V); \
    if ((IW) < 0) { \
        const float2 f = __half22float2(cc); \
        a0 += fmaxf(f.x, 0.f); a1 += fmaxf(f.y, 0.f); \
        cc = zero2; \
    } }
#define LOADI(Pa, Pb, Pc, Pd, kk) { \
    Pa = *reinterpret_cast<const int4*>(items + (kk)); \
    Pb = *reinterpret_cast<const int4*>(items + (kk) + 4); \
    Pc = *reinterpret_cast<const int4*>(items + (kk) + 8); \
    Pd = *reinterpret_cast<const int4*>(items + (kk) + 12); }
#define GATHER16(V, Pa, Pb, Pc, Pd) { \
    V[0] = GATH(Pa.x);  V[1] = GATH(Pa.y);  V[2]  = GATH(Pa.z);  V[3]  = GATH(Pa.w); \
    V[4] = GATH(Pb.x);  V[5] = GATH(Pb.y);  V[6]  = GATH(Pb.z);  V[7]  = GATH(Pb.w); \
    V[8] = GATH(Pc.x);  V[9] = GATH(Pc.y);  V[10] = GATH(Pc.z);  V[11] = GATH(Pc.w); \
    V[12] = GATH(Pd.x); V[13] = GATH(Pd.y); V[14] = GATH(Pd.z);  V[15] = GATH(Pd.w); }
#define ACC16(V, Pa, Pb, Pc, Pd) { \
    ACC(Pa.x, V[0]);  ACC(Pa.y, V[1]);  ACC(Pa.z, V[2]);   ACC(Pa.w, V[3]); \
    ACC(Pb.x, V[4]);  ACC(Pb.y, V[5]);  ACC(Pb.z, V[6]);   ACC(Pb.w, V[7]); \
    ACC(Pc.x, V[8]);  ACC(Pc.y, V[9]);  ACC(Pc.z, V[10]);  ACC(Pc.w, V[11]); \
    ACC(Pd.x, V[12]); ACC(Pd.y, V[13]); ACC(Pd.z, V[14]);  ACC(Pd.w, V[15]); }

    // head: align k to 16 (64 B scalar-load alignment)
    while (k < kend && (k & 15)) {
        const int iw = items[k];
        const __half2 v = GATH(iw);
        ACC(iw, v);
        ++k;
    }

    if (k + 32 <= kend) {
        int4 Aa, Ab, Ac, Ad, Ba, Bb, Bc, Bd;
        __half2 u[16], v[16];
        LOADI(Aa, Ab, Ac, Ad, k);
        GATHER16(u, Aa, Ab, Ac, Ad);
        LOADI(Ba, Bb, Bc, Bd, k + 16);
        k += 32;
        for (;;) {
            // phase 1: issue B's gathers, drain A
            GATHER16(v, Ba, Bb, Bc, Bd);
            ACC16(u, Aa, Ab, Ac, Ad);
            if (k + 16 <= kend) { LOADI(Aa, Ab, Ac, Ad, k); k += 16; }
            else { ACC16(v, Ba, Bb, Bc, Bd); break; }
            // phase 2: issue A's gathers, drain B
            GATHER16(u, Aa, Ab, Ac, Ad);
            ACC16(v, Ba, Bb, Bc, Bd);
            if (k + 16 <= kend) { LOADI(Ba, Bb, Bc, Bd, k); k += 16; }
            else { ACC16(u, Aa, Ab, Ac, Ad); break; }
        }
    }
    // tail
    while (k < kend) {
        const int iw = items[k];
        const __half2 v = GATH(iw);
        ACC(iw, v);
        ++k;
    }

    {   // range ends node-aligned -> cc==0; relu(0)=0 safe
        const float2 f = __half22float2(cc);
        a0 += fmaxf(f.x, 0.f);
        a1 += fmaxf(f.y, 0.f);
    }

    __shared__ float red[4][DDIM];
    red[wv][lane * 2 + 0] = a0;
    red[wv][lane * 2 + 1] = a1;
    __syncthreads();
    const int tid = threadIdx.x;
    if (tid < DDIM) {
        partials[(size_t)blockIdx.x * DDIM + tid] =
            red[0][tid] + red[1][tid] + red[2][tid] + red[3][tid];
    }
}

// ---------------- Kernel C: reduce partials + last-block softmax ----------------
__global__ __launch_bounds__(256) void reduce_softmax(
    const float* __restrict__ partials, float* __restrict__ out2,
    float* __restrict__ out, int* __restrict__ done, int nb)
{
    const int tid = threadIdx.x;
    const int d = tid & (DDIM - 1);
    const int h = tid >> 7;                  // 0..1
    {
        const int rows = nb / RED_BLOCKS;    // 32
        const int r0 = blockIdx.x * rows;
        float s = 0.f;
        for (int r = r0 + h; r < r0 + rows; r += 2)
            s += partials[(size_t)r * DDIM + d];
        __shared__ float red[2][DDIM];
        red[h][d] = s;
        __syncthreads();
        if (tid < DDIM)
            out2[(size_t)blockIdx.x * DDIM + tid] = red[0][tid] + red[1][tid];
    }
    __threadfence();
    __shared__ int isLast;
    if (tid == 0) {
        const int v = atomicAdd(done, 1);
        isLast = (v == RED_BLOCKS - 1) ? 1 : 0;
    }
    __syncthreads();
    if (!isLast) return;
    __threadfence();                          // acquire

    float s = 0.f;
    for (int b = h; b < RED_BLOCKS; b += 2)
        s += out2[(size_t)b * DDIM + d];
    __shared__ float r2[2][DDIM];
    r2[h][d] = s;
    __syncthreads();

    __shared__ float vec[DDIM];
    __shared__ float tmp[DDIM];
    if (tid < DDIM) { const float v = r2[0][tid] + r2[1][tid]; vec[tid] = v; tmp[tid] = v; }
    __syncthreads();
    for (int o = 64; o > 0; o >>= 1) {
        if (tid < o) tmp[tid] = fmaxf(tmp[tid], tmp[tid + o]);
        __syncthreads();
    }
    const float mx = tmp[0];
    __syncthreads();
    float ev = 0.f;
    if (tid < DDIM) { ev = expf(vec[tid] - mx); tmp[tid] = ev; }
    __syncthreads();
    for (int o = 64; o > 0; o >>= 1) {
        if (tid < o) tmp[tid] += tmp[tid + o];
        __syncthreads();
    }
    if (tid < DDIM) out[tid] = ev / tmp[0];
}

extern "C" void kernel_launch(void* const* d_in, const int* in_sizes, int n_in,
                              void* d_out, int out_size, void* d_ws, size_t ws_size,
                              hipStream_t stream) {
    const float* impact        = (const float*)d_in[0];
    const float* W             = (const float*)d_in[1];
    const float* Mm            = (const float*)d_in[2];
    const int*   node_ids      = (const int*)d_in[3];
    const int*   neighbor_ids  = (const int*)d_in[4];
    const int*   neighbor_segs = (const int*)d_in[5];

    const int T = in_sizes[0] / DDIM;   // 10000
    const int N = in_sizes[3];          // 50000
    const int E = in_sizes[4];          // 800000
    const int K = N + E;

    char* ws = (char*)d_ws;
    size_t off = 0;
    const int whoff = (int)off;
    __half* WhH = (__half*)(ws + off);  off += (size_t)T * DDIM * sizeof(__half);   // 2.56 MB
    const int mhoff = (int)off;
    __half* MhH = (__half*)(ws + off);  off += (size_t)T * DDIM * sizeof(__half);   // 2.56 MB
    float* partials = (float*)(ws + off); off += (size_t)ACC_BLOCKS * DDIM * sizeof(float);
    float* part2    = (float*)(ws + off); off += (size_t)RED_BLOCKS * DDIM * sizeof(float);
    int*   done     = (int*)(ws + off);   off += 256;
    off = (off + 255) & ~(size_t)255;                      // align for scalar item loads
    int*   items    = (int*)(ws + off);   off += (size_t)(K + 32) * sizeof(int);
    int*   wstart   = (int*)(ws + off);   off += (size_t)(NWALK + 1) * sizeof(int);
    float* outf     = (float*)d_out;

    const int PB    = (T + 31) / 32;                       // precompute blocks (313)
    const int PREPB = (E + NWALK + 1 + 255) / 256;         // prep blocks (incl. wstart)

    fat_prep_precompute<<<PB + PREPB, 256, 0, stream>>>(
        impact, W, Mm, WhH, MhH, neighbor_segs, node_ids, neighbor_ids,
        items, wstart, done, T, N, E, PB, whoff, mhoff);
    accumulate_items<<<ACC_BLOCKS, 256, 0, stream>>>(ws, items, wstart, partials);
    reduce_softmax<<<RED_BLOCKS, 256, 0, stream>>>(partials, part2, outf, done, ACC_BLOCKS);
}